// Round 12
// baseline (219.046 us; speedup 1.0000x reference)
//
#include <hip/hip_runtime.h>
#include <hip/hip_fp16.h>

// ---------------------------------------------------------------------------
// GCN forward on MI355X — round 32.
//  * R30/R31 post-mortem: the run-based scan's equality guard
//    (bat[tid+off]==bg) is only segment-correct for SORTED sequences;
//    degree-sorting scrambles bats bucket-locally -> non-contiguous repeats
//    merged + double-counted (absmax 1.27e-3).  Rule: doubling scans need
//    explicit flag propagation, not value-equality guards.
//  * R32: pool scan is now a TRUE segmented suffix scan with the standard
//    (sum, ended) operator: s += (!f) ? s_nbr : 0; f = f ? f : f_nbr.
//    Correct for arbitrary sequences (verified on [5,7,5],[5,5,7],[5,5,5,7]).
//  * Everything else identical to R30: degree-CLASS-sorted slots (waves see
//    near-uniform degrees), slot_x indirection, fixed arenas, R29 layers.
// ---------------------------------------------------------------------------

#define DD 64          // feature dim
#define BKT 256        // nodes per bucket
#define MAXK 1024      // LDS hist capacity (K <= 1024)
#define NBLK 256       // partition chunks
#define BTE 1024       // threads/block for fused fill
#define SRCMASK 0x3FFFF  // low 18 bits = src slot id
#define PCAP 4096      // pairbuf slots per bucket (lambda=2048 + 45 sigma)
#define CCAP 4880      // csr ints per bucket (PCAP + 3*256 pad + 16), %4==0
#define CHCAP 6656     // LDS chunk-staging capacity (CH = E/256 = 6250)

typedef _Float16 half8_t __attribute__((ext_vector_type(8)));
typedef float float4_t __attribute__((ext_vector_type(4)));
union F4H8 { float4 f; half8_t h; };
union H8   { float4 f; __half2 h[4]; };

static __device__ __forceinline__ void atomAddF(float* p, float v) {
    unsafeAtomicAdd(p, v);   // global_atomic_add_f32 on gfx950
}

// ---- P0: cursors to fixed bases, outacc zero, fp16 conversions ------------
__global__ __launch_bounds__(256) void prep_kernel(
        const float2* __restrict__ table2, __half2* __restrict__ th2, int n2,
        const float* __restrict__ W1, const float* __restrict__ W2,
        __half* __restrict__ w1t, __half* __restrict__ w2t,
        float* __restrict__ outacc, int G2, int* __restrict__ bcur, int K) {
    int gid = blockIdx.x * 256 + threadIdx.x;
    int stride = gridDim.x * 256;
    for (int i = gid; i < K; i += stride) bcur[i] = i * PCAP;
    for (int i = gid; i < G2; i += stride) outacc[i] = 0.f;
    for (int i = gid; i < n2; i += stride)
        th2[i] = __float22half2_rn(table2[i]);
    for (int i = gid; i < DD * DD; i += stride) {
        int n = i >> 6, k = i & 63;
        w1t[i] = __float2half(W1[k * DD + n]);   // WT[n][k]
        w2t[i] = __float2half(W2[k * DD + n]);
    }
}

// ---- P1: fused count + reserve + place; chunk staged in LDS ---------------
__global__ __launch_bounds__(BTE) void fused_fill_kernel(
        const int* __restrict__ src, const int* __restrict__ dst, int E, int CH,
        int* __restrict__ bcur, int* __restrict__ pairbuf, int K) {
    __shared__ int lh[MAXK];            // histogram, then cursors
    __shared__ int lpk[CHCAP];          // packed pair: s | (d&255)<<24
    __shared__ unsigned short lbk[CHCAP];   // bucket id: d >> 8
    int tid = threadIdx.x;
    for (int i = tid; i < K; i += BTE) lh[i] = 0;
    __syncthreads();
    int e0 = blockIdx.x * CH;
    int e1 = min(E, e0 + CH);
    int L = e1 - e0;
    bool fits = (L <= CHCAP);
    if (fits) {
        for (int i = tid; i < L; i += BTE) {
            int s = src[e0 + i], d = dst[e0 + i];
            unsigned b = ((unsigned)d) >> 8;
            lpk[i] = s | ((d & 255) << 24);
            lbk[i] = (unsigned short)b;
            atomicAdd(&lh[b], 1);
        }
    } else {
        for (int e = e0 + tid; e < e1; e += BTE)
            atomicAdd(&lh[((unsigned)dst[e]) >> 8], 1);
    }
    __syncthreads();
    for (int b = tid; b < K; b += BTE) {
        int c = lh[b];
        lh[b] = (c > 0) ? atomicAdd(&bcur[b], c) : 0;   // reserve range
    }
    __syncthreads();
    if (fits) {
        for (int i = tid; i < L; i += BTE) {
            int pos = atomicAdd(&lh[lbk[i]], 1);
            pairbuf[pos] = lpk[i];
        }
    } else {
        for (int e = e0 + tid; e < e1; e += BTE) {
            int s = src[e], d = dst[e];
            int pos = atomicAdd(&lh[((unsigned)d) >> 8], 1);
            pairbuf[pos] = s | ((d & 255) << 24);
        }
    }
}

// ---- P2a: per-bucket degree count + CLASS SORT + per-slot metadata --------
// rank = class-histogram position (class = quad count nq, clamped 15).
// slot = node0 + rank.  Emits rowinfo/xd/dinvh/bats by SLOT, slot_x by NODE,
// sentinel pads (csr[t]=N for t in [c,pc)), and zeroes for index N.
__global__ __launch_bounds__(256) void sort_csr_kernel(
        const int* __restrict__ pairbuf, const int* __restrict__ bcur,
        const int* __restrict__ x, const int* __restrict__ batch,
        int2* __restrict__ rowinfo, float2* __restrict__ xd,
        __half* __restrict__ dinvh, int* __restrict__ slot_x,
        int* __restrict__ bats, int* __restrict__ csr_src,
        __half* __restrict__ g1h, int N) {
    __shared__ int cnt[256], basel[256], sc[256];
    __shared__ int clscnt[16], clsbase[16];
    int tid = threadIdx.x;
    int b = blockIdx.x;
    int node0 = b << 8;
    int V = min(256, N - node0);        // valid nodes in this bucket
    cnt[tid] = 0;
    if (tid < 16) clscnt[tid] = 0;
    __syncthreads();
    int bb0 = b * PCAP;
    int L = bcur[b] - bb0;
    for (int i = tid; i < L; i += 256)
        atomicAdd(&cnt[((unsigned)pairbuf[bb0 + i]) >> 24], 1);
    __syncthreads();
    int c  = cnt[tid];
    int pc = (c + 3) & ~3;              // padded count
    int cls = min(pc >> 2, 15);
    int intra = 0;
    if (tid < V) intra = atomicAdd(&clscnt[cls], 1);
    basel[tid] = 0;
    __syncthreads();
    if (tid == 0) {
        int run = 0;
        #pragma unroll
        for (int k = 0; k < 16; ++k) { clsbase[k] = run; run += clscnt[k]; }
    }
    __syncthreads();
    int rank = (tid < V) ? (clsbase[cls] + intra) : 0;
    if (tid < V) basel[rank] = pc;      // pc scattered into rank order
    __syncthreads();
    if (tid < 64) {                     // exclusive scan basel -> sc
        int carry = 0;
        for (int cc = 0; cc < 4; ++cc) {
            int orig = basel[cc * 64 + tid];
            int v = orig;
            #pragma unroll
            for (int off = 1; off < 64; off <<= 1) {
                int t = __shfl_up(v, off);
                if (tid >= off) v += t;
            }
            int tot = __shfl(v, 63);
            sc[cc * 64 + tid] = v - orig + carry;
            carry += tot;
        }
    }
    __syncthreads();
    int cb0 = b * CCAP;                 // fixed, 16B-aligned bucket region
    int node = node0 + tid;
    if (tid < V) {
        int slot = node0 + rank;
        int myBase = cb0 + sc[rank];
        rowinfo[slot] = make_int2(myBase, pc);
        float di = rsqrtf((float)c + 1.0f);
        int xv = x[node];
        xd[slot] = make_float2(di, __int_as_float(xv));
        dinvh[slot] = __float2half(di);
        bats[slot] = batch[node];
        slot_x[node] = slot | (xv << 18);
        for (int t = c; t < pc; ++t) csr_src[myBase + t] = N;   // sentinel pad
    } else if (node == N) {
        xd[N] = make_float2(0.0f, __int_as_float(0));           // zero weight
        dinvh[N] = __float2half(0.0f);
        float2* z = (float2*)(g1h + (size_t)N * DD);            // zero row N
        for (int t = 0; t < DD / 4; ++t) z[t] = make_float2(0.f, 0.f);
    }
}

// ---- P2b: placement — csr[pos] = slot_x[src] (slot-space entries) ---------
__global__ __launch_bounds__(256) void place_csr_kernel(
        const int* __restrict__ pairbuf, const int* __restrict__ bcur,
        const int* __restrict__ slot_x, const int2* __restrict__ rowinfo,
        int* __restrict__ csr_src, int N) {
    __shared__ int curl[256];
    __shared__ unsigned char lrank[256];
    int tid = threadIdx.x;
    int b = blockIdx.x;
    int node0 = b << 8;
    int V = min(256, N - node0);
    if (tid < V) {
        int sx = slot_x[node0 + tid];
        int rank = (sx & SRCMASK) - node0;
        lrank[tid] = (unsigned char)rank;
        curl[rank] = rowinfo[sx & SRCMASK].x;   // row base for this slot
    }
    __syncthreads();
    int bb0 = b * PCAP;
    int L = bcur[b] - bb0;
    for (int i = tid; i < L; i += 256) {
        int pk = pairbuf[bb0 + i];
        int loc = ((unsigned)pk) >> 24;
        int s = pk & 0x00FFFFFF;
        int pos = atomicAdd(&curl[lrank[loc]], 1);
        csr_src[pos] = slot_x[s];
    }
}

// ---------------- layer 1: agg from fp16 table, MFMA MLP, g1h = f16(dv*h1) --
// 8 lanes/node, b128 chunks; Hs stride 9 (bank-conflict pad).
// All csr quads (c0..c3) loaded at entry; rows are degree-sorted slots.
#define L1_BODY4(sA)                                                          \
    do {                                                                      \
        unsigned a0 = (unsigned)(sA).x, a1 = (unsigned)(sA).y;                \
        unsigned a2 = (unsigned)(sA).z, a3 = (unsigned)(sA).w;                \
        H8 u0, u1, u2, u3;                                                    \
        u0.f = th4[(size_t)(a0 >> 18) * 8 + j3];                              \
        u1.f = th4[(size_t)(a1 >> 18) * 8 + j3];                              \
        u2.f = th4[(size_t)(a2 >> 18) * 8 + j3];                              \
        u3.f = th4[(size_t)(a3 >> 18) * 8 + j3];                              \
        __half2 w0 = __half2half2(dinvh[a0 & SRCMASK]);                       \
        __half2 w1 = __half2half2(dinvh[a1 & SRCMASK]);                       \
        __half2 w2 = __half2half2(dinvh[a2 & SRCMASK]);                       \
        __half2 w3 = __half2half2(dinvh[a3 & SRCMASK]);                       \
        _Pragma("unroll")                                                     \
        for (int t = 0; t < 4; ++t) {                                         \
            acc0.h[t] = __hfma2(w0, u0.h[t], acc0.h[t]);                      \
            acc1.h[t] = __hfma2(w1, u1.h[t], acc1.h[t]);                      \
            acc2.h[t] = __hfma2(w2, u2.h[t], acc2.h[t]);                      \
            acc3.h[t] = __hfma2(w3, u3.h[t], acc3.h[t]);                      \
        }                                                                     \
    } while (0)

__global__ __launch_bounds__(256, 8) void layer1_kernel(
        const int2* __restrict__ rowinfo,
        const int* __restrict__ csr_src, const float2* __restrict__ xd,
        const __half* __restrict__ dinvh,
        const float4* __restrict__ th4, const __half* __restrict__ wt,
        const float* __restrict__ bias, __half* __restrict__ g1h, int N) {
    __shared__ float4 Hs4[32 * 9];   // padded stride 9
    __shared__ float dvs[32];
    int row0 = blockIdx.x * 32;
    int tid = threadIdx.x;
    int node_l = tid >> 3, j3 = tid & 7;
    int node = row0 + node_l;
    H8 acc0, acc1, acc2, acc3;
    acc0.f = make_float4(0.f, 0.f, 0.f, 0.f);
    acc1.f = acc0.f; acc2.f = acc0.f; acc3.f = acc0.f;
    __half2 dh = __float2half2_rn(0.f);
    if (node < N) {
        float2 sxd = xd[node];
        float di = sxd.x;
        if (j3 == 0) dvs[node_l] = di;
        dh = __float2half2_rn(di);
        int2 ri = rowinfo[node];
        const int4* cs = (const int4*)(csr_src + ri.x);
        int nq = ri.y >> 2;
        int4 c0 = {0, 0, 0, 0}, c1 = c0, c2 = c0, c3 = c0;
        if (nq > 0) c0 = cs[0];
        if (nq > 1) c1 = cs[1];
        if (nq > 2) c2 = cs[2];
        if (nq > 3) c3 = cs[3];
        H8 tv; tv.f = th4[(size_t)__float_as_int(sxd.y) * 8 + j3];
        acc0.h[0] = __hmul2(dh, tv.h[0]); acc0.h[1] = __hmul2(dh, tv.h[1]);
        acc0.h[2] = __hmul2(dh, tv.h[2]); acc0.h[3] = __hmul2(dh, tv.h[3]);
        if (nq > 0) L1_BODY4(c0);
        if (nq > 1) L1_BODY4(c1);
        if (nq > 2) L1_BODY4(c2);
        if (nq > 3) L1_BODY4(c3);
        for (int q = 4; q < nq; ++q) {   // rare tail: deg > 16
            int4 cq = cs[q];
            L1_BODY4(cq);
        }
        #pragma unroll
        for (int t = 0; t < 4; ++t)
            acc0.h[t] = __hmul2(dh, __hadd2(__hadd2(acc0.h[t], acc1.h[t]),
                                            __hadd2(acc2.h[t], acc3.h[t])));
    }
    Hs4[node_l * 9 + j3] = acc0.f;
    __syncthreads();

    // MFMA MLP: 2 tiles of 16 rows; each wave does cols wave*16..+15, K=64.
    int wave = tid >> 6, lane = tid & 63;
    int m = lane & 15, quad = lane >> 4;
    int ncol = wave * 16 + m;
    F4H8 b0, b1;
    const float4* WT4 = (const float4*)wt;
    b0.f = WT4[ncol * 8 + quad];
    b1.f = WT4[ncol * 8 + 4 + quad];
    float bb_ = bias[ncol];
    #pragma unroll
    for (int t = 0; t < 2; ++t) {
        F4H8 a0, a1;
        a0.f = Hs4[(t * 16 + m) * 9 + quad];
        a1.f = Hs4[(t * 16 + m) * 9 + 4 + quad];
        float4_t acc = {0.f, 0.f, 0.f, 0.f};
        acc = __builtin_amdgcn_mfma_f32_16x16x32_f16(a0.h, b0.h, acc, 0, 0, 0);
        acc = __builtin_amdgcn_mfma_f32_16x16x32_f16(a1.h, b1.h, acc, 0, 0, 0);
        #pragma unroll
        for (int reg = 0; reg < 4; ++reg) {
            int row = t * 16 + quad * 4 + reg;
            int grow = row0 + row;
            if (grow < N) {
                float h = fmaxf(acc[reg] + bb_, 0.0f);
                g1h[(size_t)grow * DD + ncol] = __float2half(dvs[row] * h);
            }
        }
    }
}

// -------- layer 2 + pool: gather g1h, MFMA MLP, Wlin dot + segmented pool ---
#define L2_BODY4(sA)                                                          \
    do {                                                                      \
        H8 u0, u1, u2, u3;                                                    \
        u0.f = g1h4[(size_t)((sA).x & SRCMASK) * 8 + j3];                     \
        u1.f = g1h4[(size_t)((sA).y & SRCMASK) * 8 + j3];                     \
        u2.f = g1h4[(size_t)((sA).z & SRCMASK) * 8 + j3];                     \
        u3.f = g1h4[(size_t)((sA).w & SRCMASK) * 8 + j3];                     \
        _Pragma("unroll")                                                     \
        for (int t = 0; t < 4; ++t) {                                         \
            acc0.h[t] = __hadd2(acc0.h[t], u0.h[t]);                          \
            acc1.h[t] = __hadd2(acc1.h[t], u1.h[t]);                          \
            acc2.h[t] = __hadd2(acc2.h[t], u2.h[t]);                          \
            acc3.h[t] = __hadd2(acc3.h[t], u3.h[t]);                          \
        }                                                                     \
    } while (0)

__global__ __launch_bounds__(256, 8) void layer2_pool_kernel(
        const int2* __restrict__ rowinfo,
        const int* __restrict__ csr_src, const float2* __restrict__ xd,
        const float4* __restrict__ g1h4, const __half* __restrict__ wt,
        const float* __restrict__ bias, const int* __restrict__ bats,
        const float* __restrict__ Wlin, float* __restrict__ outacc, int N) {
    __shared__ float4 Hs4[32 * 9];       // padded stride 9
    __shared__ float lp0[128], lp1[128]; // [wave][row]
    __shared__ float p0s[32], p1s[32];
    __shared__ int   bat[32];
    int row0 = blockIdx.x * 32;
    int tid = threadIdx.x;
    int node_l = tid >> 3, j3 = tid & 7;
    int node = row0 + node_l;
    H8 acc0, acc1, acc2, acc3;
    acc0.f = make_float4(0.f, 0.f, 0.f, 0.f);
    acc1.f = acc0.f; acc2.f = acc0.f; acc3.f = acc0.f;
    if (node < N) {
        float di = xd[node].x;
        int2 ri = rowinfo[node];
        const int4* cs = (const int4*)(csr_src + ri.x);
        int nq = ri.y >> 2;
        int4 c0 = {0, 0, 0, 0}, c1 = c0, c2 = c0, c3 = c0;
        if (nq > 0) c0 = cs[0];
        if (nq > 1) c1 = cs[1];
        if (nq > 2) c2 = cs[2];
        if (nq > 3) c3 = cs[3];
        acc0.f = g1h4[(size_t)node * 8 + j3];   // self term, weight 1
        if (nq > 0) L2_BODY4(c0);
        if (nq > 1) L2_BODY4(c1);
        if (nq > 2) L2_BODY4(c2);
        if (nq > 3) L2_BODY4(c3);
        for (int q = 4; q < nq; ++q) {   // rare tail: deg > 16
            int4 cq = cs[q];
            L2_BODY4(cq);
        }
        __half2 dih = __float2half2_rn(di);
        #pragma unroll
        for (int t = 0; t < 4; ++t)
            acc0.h[t] = __hmul2(dih, __hadd2(__hadd2(acc0.h[t], acc1.h[t]),
                                             __hadd2(acc2.h[t], acc3.h[t])));
    }
    Hs4[node_l * 9 + j3] = acc0.f;
    __syncthreads();

    int wave = tid >> 6, lane = tid & 63;
    int m = lane & 15, quad = lane >> 4;
    int ncol = wave * 16 + m;
    F4H8 b0, b1;
    const float4* WT4 = (const float4*)wt;
    b0.f = WT4[ncol * 8 + quad];
    b1.f = WT4[ncol * 8 + 4 + quad];
    float bb_  = bias[ncol];
    float wl0 = Wlin[ncol * 2 + 0];
    float wl1 = Wlin[ncol * 2 + 1];
    #pragma unroll
    for (int t = 0; t < 2; ++t) {
        F4H8 a0, a1;
        a0.f = Hs4[(t * 16 + m) * 9 + quad];
        a1.f = Hs4[(t * 16 + m) * 9 + 4 + quad];
        float4_t acc = {0.f, 0.f, 0.f, 0.f};
        acc = __builtin_amdgcn_mfma_f32_16x16x32_f16(a0.h, b0.h, acc, 0, 0, 0);
        acc = __builtin_amdgcn_mfma_f32_16x16x32_f16(a1.h, b1.h, acc, 0, 0, 0);
        #pragma unroll
        for (int reg = 0; reg < 4; ++reg) {
            int row = t * 16 + quad * 4 + reg;
            int grow = row0 + row;
            float h = (grow < N) ? fmaxf(acc[reg] + bb_, 0.0f) : 0.0f;
            float p0 = h * wl0;
            float p1 = h * wl1;
            #pragma unroll
            for (int off = 8; off >= 1; off >>= 1) {   // sum over 16 cols (m)
                p0 += __shfl_xor(p0, off);
                p1 += __shfl_xor(p1, off);
            }
            if (m == 0) {
                lp0[wave * 32 + row] = p0;
                lp1[wave * 32 + row] = p1;
            }
        }
    }
    __syncthreads();
    if (tid < 32) {
        int grow = row0 + tid;
        p0s[tid] = lp0[tid] + lp0[32 + tid] + lp0[64 + tid] + lp0[96 + tid];
        p1s[tid] = lp1[tid] + lp1[32 + tid] + lp1[64 + tid] + lp1[96 + tid];
        bat[tid] = (grow < N) ? bats[grow] : -1;
    }
    __syncthreads();
    if (tid < 32) {
        // TRUE segmented suffix scan in registers: (sum, ended) operator.
        // s += (!f) ? s_nbr : 0; f = f ? f : f_nbr.  Correct for arbitrary
        // bat sequences; one atomic per maximal run head.
        float s0 = p0s[tid], s1 = p1s[tid];
        int bg = bat[tid];
        int f = (tid == 31) || (bat[tid + 1] != bg);   // run ends at tid
        #pragma unroll
        for (int off = 1; off < 32; off <<= 1) {
            float t0 = __shfl_down(s0, off);
            float t1 = __shfl_down(s1, off);
            int   tf = __shfl_down(f, off);
            if (tid + off < 32 && !f) {
                s0 += t0;
                s1 += t1;
                f = tf;
            }
        }
        bool head = (bg >= 0) && (tid == 0 || bat[tid - 1] != bg);
        if (head) {
            atomAddF(&outacc[bg * 2 + 0], s0);
            atomAddF(&outacc[bg * 2 + 1], s1);
        }
    }
}

// counts via binary search on sorted batch; then divide + blin
__global__ void final_kernel(const float* __restrict__ outacc,
                             const int* __restrict__ batch,
                             const float* __restrict__ blin,
                             float* __restrict__ out, int G, int N) {
    int t = blockIdx.x * blockDim.x + threadIdx.x;
    if (t >= G * 2) return;
    int g = t >> 1, c = t & 1;
    int lo = 0, hi = N;
    while (lo < hi) { int m = (lo + hi) >> 1; if (batch[m] < g) lo = m + 1; else hi = m; }
    int lo2 = lo, hi2 = N;
    while (lo2 < hi2) { int m = (lo2 + hi2) >> 1; if (batch[m] < g + 1) lo2 = m + 1; else hi2 = m; }
    float cnt = (float)(lo2 - lo);
    out[t] = outacc[t] / fmaxf(cnt, 1.0f) + blin[c];
}

extern "C" void kernel_launch(void* const* d_in, const int* in_sizes, int n_in,
                              void* d_out, int out_size, void* d_ws, size_t ws_size,
                              hipStream_t stream) {
    const int*   x      = (const int*)d_in[0];
    const int*   ei     = (const int*)d_in[1];   // [2,E] row-major
    const int*   batch  = (const int*)d_in[3];
    const float* table  = (const float*)d_in[4];
    const float* W1     = (const float*)d_in[5];
    const float* b1     = (const float*)d_in[6];
    const float* W2     = (const float*)d_in[7];
    const float* b2     = (const float*)d_in[8];
    const float* Wlin   = (const float*)d_in[9];
    const float* blin   = (const float*)d_in[10];
    float* out = (float*)d_out;

    const int N = in_sizes[0];
    const int E = in_sizes[2];          // edge_type count == E
    const int G = out_size / 2;
    const int TBL = in_sizes[4];        // VOCAB*DD floats

    const int* src = ei;
    const int* dst = ei + E;

    const int K = (N + BKT - 1) / BKT;  // buckets
    const int CH = (E + NBLK - 1) / NBLK;

    // workspace layout (keep 16-B alignment for b128 reads)
    __half* g1h     = (__half*)d_ws;                      // (N+1)*64 halves
    __half* th      = g1h + (size_t)(N + 1) * DD;         // TBL halves
    __half* w1t     = th + TBL;                           // 4096 halves
    __half* w2t     = w1t + DD * DD;                      // 4096 halves
    int*    pairbuf = (int*)(w2t + DD * DD);              // K*PCAP ints
    int*    csr_src = pairbuf + (size_t)K * PCAP;         // K*CCAP ints
    int2*   rowinfo = (int2*)(csr_src + (size_t)K * CCAP);// N int2
    float2* xd      = (float2*)(rowinfo + N);             // N+1 float2
    __half* dinvh   = (__half*)(xd + N + 1);              // N+1 halves (pad even)
    float*  outacc  = (float*)(dinvh + (size_t)((N + 2) & ~1)); // 2G
    int*    bcur    = (int*)(outacc + 2 * G);             // K
    int*    slot_x  = bcur + K;                           // N
    int*    bats    = slot_x + N;                         // N

    const int BT = 256;

    // partition: prep -> fused fill -> degree-sort metadata -> place
    prep_kernel<<<2048, BT, 0, stream>>>((const float2*)table, (__half2*)th,
                                         TBL / 2, W1, W2, w1t, w2t,
                                         outacc, 2 * G, bcur, K);
    fused_fill_kernel<<<NBLK, BTE, 0, stream>>>(src, dst, E, CH, bcur,
                                                pairbuf, K);
    sort_csr_kernel<<<K, BT, 0, stream>>>(pairbuf, bcur, x, batch, rowinfo,
                                          xd, dinvh, slot_x, bats, csr_src,
                                          g1h, N);
    place_csr_kernel<<<K, BT, 0, stream>>>(pairbuf, bcur, slot_x, rowinfo,
                                           csr_src, N);

    // layer 1 (embed+agg+MFMA-MLP+relu fused; writes g1h = fp16(dinv*h1))
    int gRow = (N + 31) / 32;
    layer1_kernel<<<gRow, BT, 0, stream>>>(rowinfo, csr_src, xd, dinvh,
                                           (const float4*)th, w1t, b1, g1h, N);
    // layer 2 (agg+MFMA-MLP+relu+pool fused)
    layer2_pool_kernel<<<gRow, BT, 0, stream>>>(rowinfo, csr_src, xd,
                                                (const float4*)g1h, w2t, b2,
                                                bats, Wlin, outacc, N);
    // final
    final_kernel<<<(G * 2 + BT - 1) / BT, BT, 0, stream>>>(outacc, batch, blin,
                                                           out, G, N);
}

// Round 13
// 204.188 us; speedup vs baseline: 1.0728x; 1.0728x over previous
//
#include <hip/hip_runtime.h>
#include <hip/hip_fp16.h>

// ---------------------------------------------------------------------------
// GCN forward on MI355X — round 33 = exact R29 revert (best: 205.2 us).
//  * R32 post-mortem: bucket-local degree-CLASS-sort regressed layer2
//    44.2 -> 47.2 us (occupancy 62 -> 51%): wave-level uniformity was bought
//    by CLUSTERING high-degree nodes into few blocks -> bimodal block times,
//    grid straggler tail.  Sort-for-SIMD must be grid-interleaved, not
//    locally clustered; and masked lanes issue no loads, so the guarded
//    bodies were cheaper than the max-of-8 model claimed.
//  * R29 accounting (closes): 2x44us harness re-poison fills (untouchable)
//    + layer2 ~43us (random 128B g1h gathers at ~4.7 TB/s L2/L3-side,
//    25.6MB working set > per-XCD L2) + layer1 ~39us + partition ~25us +
//    final 2us + gaps = ~205us.  All structural levers tested: launch cuts
//    x3 (neutral), traffic cuts x2 (neutral), divergence sort (regressed),
//    sw-pipelining x2 (regressed/neutral), megakernel (3x regression).
// ---------------------------------------------------------------------------

#define DD 64          // feature dim
#define BKT 256        // nodes per bucket
#define MAXK 1024      // LDS hist capacity (K <= 1024)
#define NBLK 256       // partition chunks
#define BTE 1024       // threads/block for fused fill
#define SRCMASK 0x3FFFF  // low 18 bits = src node id
#define PBUF_CAP 4096  // LDS staging capacity in build_csr
#define PCAP 4096      // pairbuf slots per bucket (lambda=2048 + 45 sigma)
#define CCAP 4880      // csr ints per bucket (PCAP + 3*256 pad + 16), %4==0
#define CHCAP 6656     // LDS chunk-staging capacity (CH = E/256 = 6250)

typedef _Float16 half8_t __attribute__((ext_vector_type(8)));
typedef float float4_t __attribute__((ext_vector_type(4)));
union F4H8 { float4 f; half8_t h; };
union H8   { float4 f; __half2 h[4]; };

static __device__ __forceinline__ void atomAddF(float* p, float v) {
    unsafeAtomicAdd(p, v);   // global_atomic_add_f32 on gfx950
}

// ---- P0: cursors to fixed bases, outacc zero, fp16 conversions ------------
__global__ __launch_bounds__(256) void prep_kernel(
        const float2* __restrict__ table2, __half2* __restrict__ th2, int n2,
        const float* __restrict__ W1, const float* __restrict__ W2,
        __half* __restrict__ w1t, __half* __restrict__ w2t,
        float* __restrict__ outacc, int G2, int* __restrict__ bcur, int K) {
    int gid = blockIdx.x * 256 + threadIdx.x;
    int stride = gridDim.x * 256;
    for (int i = gid; i < K; i += stride) bcur[i] = i * PCAP;
    for (int i = gid; i < G2; i += stride) outacc[i] = 0.f;
    for (int i = gid; i < n2; i += stride)
        th2[i] = __float22half2_rn(table2[i]);
    for (int i = gid; i < DD * DD; i += stride) {
        int n = i >> 6, k = i & 63;
        w1t[i] = __float2half(W1[k * DD + n]);   // WT[n][k]
        w2t[i] = __float2half(W2[k * DD + n]);
    }
}

// ---- P1: fused count + reserve + place; chunk staged in LDS ---------------
__global__ __launch_bounds__(BTE) void fused_fill_kernel(
        const int* __restrict__ src, const int* __restrict__ dst, int E, int CH,
        int* __restrict__ bcur, int* __restrict__ pairbuf, int K) {
    __shared__ int lh[MAXK];            // histogram, then cursors
    __shared__ int lpk[CHCAP];          // packed pair: s | (d&255)<<24
    __shared__ unsigned short lbk[CHCAP];   // bucket id: d >> 8
    int tid = threadIdx.x;
    for (int i = tid; i < K; i += BTE) lh[i] = 0;
    __syncthreads();
    int e0 = blockIdx.x * CH;
    int e1 = min(E, e0 + CH);
    int L = e1 - e0;
    bool fits = (L <= CHCAP);
    if (fits) {
        for (int i = tid; i < L; i += BTE) {
            int s = src[e0 + i], d = dst[e0 + i];
            unsigned b = ((unsigned)d) >> 8;
            lpk[i] = s | ((d & 255) << 24);
            lbk[i] = (unsigned short)b;
            atomicAdd(&lh[b], 1);
        }
    } else {
        for (int e = e0 + tid; e < e1; e += BTE)
            atomicAdd(&lh[((unsigned)dst[e]) >> 8], 1);
    }
    __syncthreads();
    for (int b = tid; b < K; b += BTE) {
        int c = lh[b];
        lh[b] = (c > 0) ? atomicAdd(&bcur[b], c) : 0;   // reserve range
    }
    __syncthreads();
    if (fits) {
        for (int i = tid; i < L; i += BTE) {
            int pos = atomicAdd(&lh[lbk[i]], 1);
            pairbuf[pos] = lpk[i];
        }
    } else {
        for (int e = e0 + tid; e < e1; e += BTE) {
            int s = src[e], d = dst[e];
            int pos = atomicAdd(&lh[((unsigned)d) >> 8], 1);
            pairbuf[pos] = s | ((d & 255) << 24);
        }
    }
}

// ---- P2: per-bucket padded CSR build from LDS-staged slice ----------------
// csr entry = src | (x[src] << 18).  Sentinel pad = N (x-part 0 -> zeroed th
// row 0, dinvh[N] = 0 -> zero weight, g1h row N zeroed -> zero layer2 term).
__global__ __launch_bounds__(256) void build_csr_kernel(
        const int* __restrict__ pairbuf, const int* __restrict__ bcur,
        const int* __restrict__ x, int2* __restrict__ rowinfo,
        float2* __restrict__ xd, __half* __restrict__ dinvh,
        int* __restrict__ csr_src, __half* __restrict__ g1h, int N) {
    __shared__ int cnt[256], basel[256], curl[256];
    __shared__ int pbuf[PBUF_CAP];
    int tid = threadIdx.x;
    int b = blockIdx.x;
    int node0 = b << 8;
    cnt[tid] = 0;
    __syncthreads();
    int bb0 = b * PCAP;
    int L   = bcur[b] - bb0;          // edges landed in this bucket
    bool fits = (L <= PBUF_CAP);
    if (fits) {
        for (int i = tid; i < L; i += 256) {
            int pk = pairbuf[bb0 + i];
            pbuf[i] = pk;
            atomicAdd(&cnt[((unsigned)pk) >> 24], 1);
        }
    } else {
        for (int i = tid; i < L; i += 256)
            atomicAdd(&cnt[((unsigned)pairbuf[bb0 + i]) >> 24], 1);
    }
    __syncthreads();
    int c  = cnt[tid];
    int pc = (c + 3) & ~3;              // padded count
    {
        __syncthreads();
        basel[tid] = pc;
        __syncthreads();
        if (tid < 64) {
            int carry = 0;
            for (int cc = 0; cc < 4; ++cc) {
                int orig = basel[cc * 64 + tid];
                int v = orig;
                #pragma unroll
                for (int off = 1; off < 64; off <<= 1) {
                    int t = __shfl_up(v, off);
                    if (tid >= off) v += t;
                }
                int tot = __shfl(v, 63);
                cnt[cc * 64 + tid] = v - orig + carry;   // exclusive
                carry += tot;
            }
        }
        __syncthreads();
    }
    int cb0 = b * CCAP;                 // fixed, 16B-aligned bucket region
    int node = node0 + tid;
    int myBase = cb0 + cnt[tid];
    curl[tid] = myBase;
    if (node < N) {
        rowinfo[node] = make_int2(myBase, pc);
        float di = rsqrtf((float)c + 1.0f);
        xd[node] = make_float2(di, __int_as_float(x[node]));
        dinvh[node] = __float2half(di);
        for (int t = c; t < pc; ++t) csr_src[myBase + t] = N;   // sentinel pad
    } else if (node == N) {
        xd[N] = make_float2(0.0f, __int_as_float(0));           // zero weight
        dinvh[N] = __float2half(0.0f);
        float2* z = (float2*)(g1h + (size_t)N * DD);            // zero row N
        for (int t = 0; t < DD / 4; ++t) z[t] = make_float2(0.f, 0.f);
    }
    __syncthreads();
    if (fits) {
        for (int i = tid; i < L; i += 256) {
            int pk = pbuf[i];
            int pos = atomicAdd(&curl[((unsigned)pk) >> 24], 1);
            int s = pk & 0x00FFFFFF;
            csr_src[pos] = (int)(((unsigned)s) | (((unsigned)x[s]) << 18));
        }
    } else {
        for (int i = tid; i < L; i += 256) {
            int pk = pairbuf[bb0 + i];
            int pos = atomicAdd(&curl[((unsigned)pk) >> 24], 1);
            int s = pk & 0x00FFFFFF;
            csr_src[pos] = (int)(((unsigned)s) | (((unsigned)x[s]) << 18));
        }
    }
}

// ---------------- layer 1: agg from fp16 table, MFMA MLP, g1h = f16(dv*h1) --
// 8 lanes/node, b128 chunks; Hs stride 9 (bank-conflict pad).
// All csr quads (c0..c3) loaded at entry — cs L2 latency paid once per node.
#define L1_BODY4(sA)                                                          \
    do {                                                                      \
        unsigned a0 = (unsigned)(sA).x, a1 = (unsigned)(sA).y;                \
        unsigned a2 = (unsigned)(sA).z, a3 = (unsigned)(sA).w;                \
        H8 u0, u1, u2, u3;                                                    \
        u0.f = th4[(size_t)(a0 >> 18) * 8 + j3];                              \
        u1.f = th4[(size_t)(a1 >> 18) * 8 + j3];                              \
        u2.f = th4[(size_t)(a2 >> 18) * 8 + j3];                              \
        u3.f = th4[(size_t)(a3 >> 18) * 8 + j3];                              \
        __half2 w0 = __half2half2(dinvh[a0 & SRCMASK]);                       \
        __half2 w1 = __half2half2(dinvh[a1 & SRCMASK]);                       \
        __half2 w2 = __half2half2(dinvh[a2 & SRCMASK]);                       \
        __half2 w3 = __half2half2(dinvh[a3 & SRCMASK]);                       \
        _Pragma("unroll")                                                     \
        for (int t = 0; t < 4; ++t) {                                         \
            acc0.h[t] = __hfma2(w0, u0.h[t], acc0.h[t]);                      \
            acc1.h[t] = __hfma2(w1, u1.h[t], acc1.h[t]);                      \
            acc2.h[t] = __hfma2(w2, u2.h[t], acc2.h[t]);                      \
            acc3.h[t] = __hfma2(w3, u3.h[t], acc3.h[t]);                      \
        }                                                                     \
    } while (0)

__global__ __launch_bounds__(256, 8) void layer1_kernel(
        const int2* __restrict__ rowinfo,
        const int* __restrict__ csr_src, const float2* __restrict__ xd,
        const __half* __restrict__ dinvh,
        const float4* __restrict__ th4, const __half* __restrict__ wt,
        const float* __restrict__ bias, __half* __restrict__ g1h, int N) {
    __shared__ float4 Hs4[32 * 9];   // padded stride 9
    __shared__ float dvs[32];
    int row0 = blockIdx.x * 32;
    int tid = threadIdx.x;
    int node_l = tid >> 3, j3 = tid & 7;
    int node = row0 + node_l;
    H8 acc0, acc1, acc2, acc3;
    acc0.f = make_float4(0.f, 0.f, 0.f, 0.f);
    acc1.f = acc0.f; acc2.f = acc0.f; acc3.f = acc0.f;
    __half2 dh = __float2half2_rn(0.f);
    if (node < N) {
        float2 sxd = xd[node];
        float di = sxd.x;
        if (j3 == 0) dvs[node_l] = di;
        dh = __float2half2_rn(di);
        int2 ri = rowinfo[node];
        const int4* cs = (const int4*)(csr_src + ri.x);
        int nq = ri.y >> 2;
        int4 c0 = {0, 0, 0, 0}, c1 = c0, c2 = c0, c3 = c0;
        if (nq > 0) c0 = cs[0];
        if (nq > 1) c1 = cs[1];
        if (nq > 2) c2 = cs[2];
        if (nq > 3) c3 = cs[3];
        H8 tv; tv.f = th4[(size_t)__float_as_int(sxd.y) * 8 + j3];
        acc0.h[0] = __hmul2(dh, tv.h[0]); acc0.h[1] = __hmul2(dh, tv.h[1]);
        acc0.h[2] = __hmul2(dh, tv.h[2]); acc0.h[3] = __hmul2(dh, tv.h[3]);
        if (nq > 0) L1_BODY4(c0);
        if (nq > 1) L1_BODY4(c1);
        if (nq > 2) L1_BODY4(c2);
        if (nq > 3) L1_BODY4(c3);
        for (int q = 4; q < nq; ++q) {   // rare tail: deg > 16
            int4 cq = cs[q];
            L1_BODY4(cq);
        }
        #pragma unroll
        for (int t = 0; t < 4; ++t)
            acc0.h[t] = __hmul2(dh, __hadd2(__hadd2(acc0.h[t], acc1.h[t]),
                                            __hadd2(acc2.h[t], acc3.h[t])));
    }
    Hs4[node_l * 9 + j3] = acc0.f;
    __syncthreads();

    // MFMA MLP: 2 tiles of 16 rows; each wave does cols wave*16..+15, K=64.
    int wave = tid >> 6, lane = tid & 63;
    int m = lane & 15, quad = lane >> 4;
    int ncol = wave * 16 + m;
    F4H8 b0, b1;
    const float4* WT4 = (const float4*)wt;
    b0.f = WT4[ncol * 8 + quad];
    b1.f = WT4[ncol * 8 + 4 + quad];
    float bb_ = bias[ncol];
    #pragma unroll
    for (int t = 0; t < 2; ++t) {
        F4H8 a0, a1;
        a0.f = Hs4[(t * 16 + m) * 9 + quad];
        a1.f = Hs4[(t * 16 + m) * 9 + 4 + quad];
        float4_t acc = {0.f, 0.f, 0.f, 0.f};
        acc = __builtin_amdgcn_mfma_f32_16x16x32_f16(a0.h, b0.h, acc, 0, 0, 0);
        acc = __builtin_amdgcn_mfma_f32_16x16x32_f16(a1.h, b1.h, acc, 0, 0, 0);
        #pragma unroll
        for (int reg = 0; reg < 4; ++reg) {
            int row = t * 16 + quad * 4 + reg;
            int grow = row0 + row;
            if (grow < N) {
                float h = fmaxf(acc[reg] + bb_, 0.0f);
                g1h[(size_t)grow * DD + ncol] = __float2half(dvs[row] * h);
            }
        }
    }
}

// -------- layer 2 + pool: gather g1h, MFMA MLP, Wlin dot + segmented pool ---
#define L2_BODY4(sA)                                                          \
    do {                                                                      \
        H8 u0, u1, u2, u3;                                                    \
        u0.f = g1h4[(size_t)((sA).x & SRCMASK) * 8 + j3];                     \
        u1.f = g1h4[(size_t)((sA).y & SRCMASK) * 8 + j3];                     \
        u2.f = g1h4[(size_t)((sA).z & SRCMASK) * 8 + j3];                     \
        u3.f = g1h4[(size_t)((sA).w & SRCMASK) * 8 + j3];                     \
        _Pragma("unroll")                                                     \
        for (int t = 0; t < 4; ++t) {                                         \
            acc0.h[t] = __hadd2(acc0.h[t], u0.h[t]);                          \
            acc1.h[t] = __hadd2(acc1.h[t], u1.h[t]);                          \
            acc2.h[t] = __hadd2(acc2.h[t], u2.h[t]);                          \
            acc3.h[t] = __hadd2(acc3.h[t], u3.h[t]);                          \
        }                                                                     \
    } while (0)

__global__ __launch_bounds__(256, 8) void layer2_pool_kernel(
        const int2* __restrict__ rowinfo,
        const int* __restrict__ csr_src, const float2* __restrict__ xd,
        const float4* __restrict__ g1h4, const __half* __restrict__ wt,
        const float* __restrict__ bias, const int* __restrict__ batch,
        const float* __restrict__ Wlin, float* __restrict__ outacc, int N) {
    __shared__ float4 Hs4[32 * 9];       // padded stride 9
    __shared__ float lp0[128], lp1[128]; // [wave][row]
    __shared__ float p0s[32], p1s[32];
    __shared__ int   bat[32];
    int row0 = blockIdx.x * 32;
    int tid = threadIdx.x;
    int node_l = tid >> 3, j3 = tid & 7;
    int node = row0 + node_l;
    H8 acc0, acc1, acc2, acc3;
    acc0.f = make_float4(0.f, 0.f, 0.f, 0.f);
    acc1.f = acc0.f; acc2.f = acc0.f; acc3.f = acc0.f;
    if (node < N) {
        float di = xd[node].x;
        int2 ri = rowinfo[node];
        const int4* cs = (const int4*)(csr_src + ri.x);
        int nq = ri.y >> 2;
        int4 c0 = {0, 0, 0, 0}, c1 = c0, c2 = c0, c3 = c0;
        if (nq > 0) c0 = cs[0];
        if (nq > 1) c1 = cs[1];
        if (nq > 2) c2 = cs[2];
        if (nq > 3) c3 = cs[3];
        acc0.f = g1h4[(size_t)node * 8 + j3];   // self term, weight 1
        if (nq > 0) L2_BODY4(c0);
        if (nq > 1) L2_BODY4(c1);
        if (nq > 2) L2_BODY4(c2);
        if (nq > 3) L2_BODY4(c3);
        for (int q = 4; q < nq; ++q) {   // rare tail: deg > 16
            int4 cq = cs[q];
            L2_BODY4(cq);
        }
        __half2 dih = __float2half2_rn(di);
        #pragma unroll
        for (int t = 0; t < 4; ++t)
            acc0.h[t] = __hmul2(dih, __hadd2(__hadd2(acc0.h[t], acc1.h[t]),
                                             __hadd2(acc2.h[t], acc3.h[t])));
    }
    Hs4[node_l * 9 + j3] = acc0.f;
    __syncthreads();

    int wave = tid >> 6, lane = tid & 63;
    int m = lane & 15, quad = lane >> 4;
    int ncol = wave * 16 + m;
    F4H8 b0, b1;
    const float4* WT4 = (const float4*)wt;
    b0.f = WT4[ncol * 8 + quad];
    b1.f = WT4[ncol * 8 + 4 + quad];
    float bb_  = bias[ncol];
    float wl0 = Wlin[ncol * 2 + 0];
    float wl1 = Wlin[ncol * 2 + 1];
    #pragma unroll
    for (int t = 0; t < 2; ++t) {
        F4H8 a0, a1;
        a0.f = Hs4[(t * 16 + m) * 9 + quad];
        a1.f = Hs4[(t * 16 + m) * 9 + 4 + quad];
        float4_t acc = {0.f, 0.f, 0.f, 0.f};
        acc = __builtin_amdgcn_mfma_f32_16x16x32_f16(a0.h, b0.h, acc, 0, 0, 0);
        acc = __builtin_amdgcn_mfma_f32_16x16x32_f16(a1.h, b1.h, acc, 0, 0, 0);
        #pragma unroll
        for (int reg = 0; reg < 4; ++reg) {
            int row = t * 16 + quad * 4 + reg;
            int grow = row0 + row;
            float h = (grow < N) ? fmaxf(acc[reg] + bb_, 0.0f) : 0.0f;
            float p0 = h * wl0;
            float p1 = h * wl1;
            #pragma unroll
            for (int off = 8; off >= 1; off >>= 1) {   // sum over 16 cols (m)
                p0 += __shfl_xor(p0, off);
                p1 += __shfl_xor(p1, off);
            }
            if (m == 0) {
                lp0[wave * 32 + row] = p0;
                lp1[wave * 32 + row] = p1;
            }
        }
    }
    __syncthreads();
    if (tid < 32) {
        int grow = row0 + tid;
        p0s[tid] = lp0[tid] + lp0[32 + tid] + lp0[64 + tid] + lp0[96 + tid];
        p1s[tid] = lp1[tid] + lp1[32 + tid] + lp1[64 + tid] + lp1[96 + tid];
        bat[tid] = (grow < N) ? batch[grow] : -1;
    }
    __syncthreads();
    if (tid < 32) {
        // Segmented suffix scan IN REGISTERS via __shfl_down (5 doubling
        // steps).  Shuffles read the neighbor's pre-update value in
        // lockstep; bat[] is read-only after the barrier above.  At each
        // head lane the result equals the serial run-walk sum (batch is
        // sorted here, so the equality guard is segment-correct).
        float s0 = p0s[tid], s1 = p1s[tid];
        int bg = bat[tid];
        #pragma unroll
        for (int off = 1; off < 32; off <<= 1) {
            float t0 = __shfl_down(s0, off);
            float t1 = __shfl_down(s1, off);
            if (tid + off < 32 && bat[tid + off] == bg) {
                s0 += t0;
                s1 += t1;
            }
        }
        bool head = (bg >= 0) && (tid == 0 || bat[tid - 1] != bg);
        if (head) {
            atomAddF(&outacc[bg * 2 + 0], s0);
            atomAddF(&outacc[bg * 2 + 1], s1);
        }
    }
}

// counts via binary search on sorted batch; then divide + blin
__global__ void final_kernel(const float* __restrict__ outacc,
                             const int* __restrict__ batch,
                             const float* __restrict__ blin,
                             float* __restrict__ out, int G, int N) {
    int t = blockIdx.x * blockDim.x + threadIdx.x;
    if (t >= G * 2) return;
    int g = t >> 1, c = t & 1;
    int lo = 0, hi = N;
    while (lo < hi) { int m = (lo + hi) >> 1; if (batch[m] < g) lo = m + 1; else hi = m; }
    int lo2 = lo, hi2 = N;
    while (lo2 < hi2) { int m = (lo2 + hi2) >> 1; if (batch[m] < g + 1) lo2 = m + 1; else hi2 = m; }
    float cnt = (float)(lo2 - lo);
    out[t] = outacc[t] / fmaxf(cnt, 1.0f) + blin[c];
}

extern "C" void kernel_launch(void* const* d_in, const int* in_sizes, int n_in,
                              void* d_out, int out_size, void* d_ws, size_t ws_size,
                              hipStream_t stream) {
    const int*   x      = (const int*)d_in[0];
    const int*   ei     = (const int*)d_in[1];   // [2,E] row-major
    const int*   batch  = (const int*)d_in[3];
    const float* table  = (const float*)d_in[4];
    const float* W1     = (const float*)d_in[5];
    const float* b1     = (const float*)d_in[6];
    const float* W2     = (const float*)d_in[7];
    const float* b2     = (const float*)d_in[8];
    const float* Wlin   = (const float*)d_in[9];
    const float* blin   = (const float*)d_in[10];
    float* out = (float*)d_out;

    const int N = in_sizes[0];
    const int E = in_sizes[2];          // edge_type count == E
    const int G = out_size / 2;
    const int TBL = in_sizes[4];        // VOCAB*DD floats

    const int* src = ei;
    const int* dst = ei + E;

    const int K = (N + BKT - 1) / BKT;  // buckets
    const int CH = (E + NBLK - 1) / NBLK;

    // workspace layout (keep 16-B alignment for b128 reads)
    __half* g1h     = (__half*)d_ws;                      // (N+1)*64 halves
    __half* th      = g1h + (size_t)(N + 1) * DD;         // TBL halves
    __half* w1t     = th + TBL;                           // 4096 halves
    __half* w2t     = w1t + DD * DD;                      // 4096 halves
    int*    pairbuf = (int*)(w2t + DD * DD);              // K*PCAP ints
    int*    csr_src = pairbuf + (size_t)K * PCAP;         // K*CCAP ints
    int2*   rowinfo = (int2*)(csr_src + (size_t)K * CCAP);// N int2
    float2* xd      = (float2*)(rowinfo + N);             // N+1 float2
    __half* dinvh   = (__half*)(xd + N + 1);              // N+1 halves (pad even)
    float*  outacc  = (float*)(dinvh + (size_t)((N + 2) & ~1)); // 2G
    int*    bcur    = (int*)(outacc + 2 * G);             // K

    const int BT = 256;

    // partition: prep -> fused fill (count+reserve+place) -> CSR sort
    prep_kernel<<<2048, BT, 0, stream>>>((const float2*)table, (__half2*)th,
                                         TBL / 2, W1, W2, w1t, w2t,
                                         outacc, 2 * G, bcur, K);
    fused_fill_kernel<<<NBLK, BTE, 0, stream>>>(src, dst, E, CH, bcur,
                                                pairbuf, K);
    build_csr_kernel<<<K, BT, 0, stream>>>(pairbuf, bcur, x, rowinfo, xd,
                                           dinvh, csr_src, g1h, N);

    // layer 1 (embed+agg+MFMA-MLP+relu fused; writes g1h = fp16(dinv*h1))
    int gRow = (N + 31) / 32;
    layer1_kernel<<<gRow, BT, 0, stream>>>(rowinfo, csr_src, xd, dinvh,
                                           (const float4*)th, w1t, b1, g1h, N);
    // layer 2 (agg+MFMA-MLP+relu+pool fused)
    layer2_pool_kernel<<<gRow, BT, 0, stream>>>(rowinfo, csr_src, xd,
                                                (const float4*)g1h, w2t, b2,
                                                batch, Wlin, outacc, N);
    // final
    final_kernel<<<(G * 2 + BT - 1) / BT, BT, 0, stream>>>(outacc, batch, blin,
                                                           out, G, N);
}